// Round 11
// baseline (255.503 us; speedup 1.0000x reference)
//
#include <hip/hip_runtime.h>
#include <cmath>

#define NN 50000
#define NP 50048
#define NE 800000
#define CD 40
#define NEG_SLOPE 0.2f
#define NITEMS (NE + NN)   // edges + self-loops
#define CHUNK 2048
#define NCH 416            // ceil(NITEMS / CHUNK)
#define NBKT 391           // node buckets of 128 (covers 50048)
#define BCAP 3072          // bucket capacity (mean 2174, +19 sigma)
#define GB1 782            // gemm blocks, 64 rows each (NP/64)
#define TB1 (3 * 64 * 256)
#define TB2 (3 * 64 * 64)
#define WPB 240            // W-pack blocks ((TB1+TB2)/256)

typedef __attribute__((ext_vector_type(8))) short s16x8;   // 8 bf16
typedef __attribute__((ext_vector_type(4))) float f32x4;   // 4 fp32 acc
typedef __attribute__((ext_vector_type(2))) float f32x2;   // packed-math pair

__device__ __forceinline__ f32x2 pk_fma(f32x2 a, f32x2 b, f32x2 c) {
#if __has_builtin(__builtin_elementwise_fma)
  return __builtin_elementwise_fma(a, b, c);
#else
  f32x2 r; r[0] = fmaf(a[0], b[0], c[0]); r[1] = fmaf(a[1], b[1], c[1]); return r;
#endif
}
__device__ __forceinline__ f32x2 pk_max(f32x2 a, f32x2 b) {
#if __has_builtin(__builtin_elementwise_max)
  return __builtin_elementwise_max(a, b);
#else
  f32x2 r; r[0] = fmaxf(a[0], b[0]); r[1] = fmaxf(a[1], b[1]); return r;
#endif
}

__device__ __forceinline__ short f2bf(float x) {  // RNE, finite
  unsigned u = __builtin_bit_cast(unsigned, x);
  u += 0x7fffu + ((u >> 16) & 1u);
  return (short)(u >> 16);
}
__device__ __forceinline__ unsigned pack2(float lo, float hi) {
  return (unsigned)(unsigned short)f2bf(lo) | ((unsigned)(unsigned short)f2bf(hi) << 16);
}
__device__ __forceinline__ float bf2f_lo(unsigned v) {
  return __builtin_bit_cast(float, v << 16);
}
__device__ __forceinline__ float bf2f_hi(unsigned v) {
  return __builtin_bit_cast(float, v & 0xffff0000u);
}
__device__ __forceinline__ void unp8(uint4 v, f32x2* f) {
  f[0] = (f32x2){bf2f_lo(v.x), bf2f_hi(v.x)};
  f[1] = (f32x2){bf2f_lo(v.y), bf2f_hi(v.y)};
  f[2] = (f32x2){bf2f_lo(v.z), bf2f_hi(v.z)};
  f[3] = (f32x2){bf2f_lo(v.w), bf2f_hi(v.w)};
}

// ====== prep_bin: W frag-pack (blocks 0..239) | edge binning (blocks 240..) ======
__global__ __launch_bounds__(256) void prep_bin(const float* __restrict__ W1l,
                                                const float* __restrict__ W1r,
                                                const float* __restrict__ L1,
                                                const float* __restrict__ W2l,
                                                const float* __restrict__ W2r,
                                                const float* __restrict__ L2,
                                                short* __restrict__ Wp1,
                                                short* __restrict__ Wp2,
                                                const int* __restrict__ ei,
                                                float* __restrict__ outE,
                                                int* __restrict__ gcur,
                                                unsigned* __restrict__ rec) {
  const int tid = threadIdx.x;
  if (blockIdx.x < WPB) {  // W pack: [kb][w][t][lane][j]
    int e = blockIdx.x * 256 + tid;
    if (e < TB1) {  // layer 1: K=256, OC=64, src [256][64]
      int kb = e / 6144, r = e % 6144;
      int w = r / 2048, r2 = r % 2048;
      int t = r2 / 512, r3 = r2 % 512;
      int lane = r3 / 8, j = r3 % 8;
      int n = t * 16 + (lane & 15);
      int k = kb * 32 + (lane >> 4) * 8 + j;
      const float* W = (w == 0) ? W1l : (w == 1) ? W1r : L1;
      Wp1[e] = f2bf(W[k * 64 + n]);
    } else {  // layer 2: K=64, OC=40 pad 64
      e -= TB1;
      int kb = e / 6144, r = e % 6144;
      int w = r / 2048, r2 = r % 2048;
      int t = r2 / 512, r3 = r2 % 512;
      int lane = r3 / 8, j = r3 % 8;
      int n = t * 16 + (lane & 15);
      int k = kb * 32 + (lane >> 4) * 8 + j;
      const float* W = (w == 0) ? W2l : (w == 1) ? W2r : L2;
      Wp2[e] = (n < 40) ? f2bf(W[k * 40 + n]) : (short)0;
    }
    return;
  }
  // ---- Phase A ----
  __shared__ unsigned sorted[CHUNK];
  __shared__ int hist[512];
  __shared__ int bcur[512];
  __shared__ int gbase[512];
  const int base = (blockIdx.x - WPB) * CHUNK;
  for (int t = tid; t < 512; t += 256) { hist[t] = 0; bcur[t] = 0; gbase[t] = 0; }
  __syncthreads();
  unsigned key[CHUNK / 256];
#pragma unroll
  for (int u = 0; u < CHUNK / 256; ++u) {
    const int j = base + u * 256 + tid;
    unsigned k = 0xFFFFFFFFu;
    if (j < NITEMS) {
      int s, d;
      if (j < NE) {
        s = ei[j]; d = ei[NE + j];
        outE[j] = (float)s; outE[NE + j] = (float)d;
      } else {
        s = j - NE; d = s;
      }
      k = ((unsigned)d << 16) | (unsigned)s;
      atomicAdd(&hist[k >> 23], 1);
    }
    key[u] = k;
  }
  __syncthreads();
  if (tid < 64) {  // exclusive scan hist[0..511], one wave
    int carry = 0;
#pragma unroll
    for (int c = 0; c < 8; ++c) {
      int v = hist[c * 64 + tid];
      int inc = v;
#pragma unroll
      for (int off = 1; off < 64; off <<= 1) {
        int tt = __shfl_up(inc, off, 64);
        if (tid >= off) inc += tt;
      }
      hist[c * 64 + tid] = carry + inc - v;
      carry += __shfl(inc, 63, 64);
    }
  }
  __syncthreads();
#pragma unroll
  for (int u = 0; u < CHUNK / 256; ++u) {
    const unsigned k = key[u];
    if (k != 0xFFFFFFFFu) {
      const int b = k >> 23;
      sorted[hist[b] + atomicAdd(&bcur[b], 1)] = k;
    }
  }
  __syncthreads();
  for (int t = tid; t < NBKT; t += 256) {
    const int c = bcur[t];
    if (c > 0) gbase[t] = atomicAdd(&gcur[t], c);
  }
  __syncthreads();
  const int cnt = min(CHUNK, NITEMS - base);
  for (int i = tid; i < cnt; i += 256) {
    const unsigned k = sorted[i];
    const int b = k >> 23;
    const int p = gbase[b] + (i - hist[b]);
    if (p < BCAP) rec[(size_t)b * BCAP + p] = k;
  }
}

// ================= gemm1 body: 64 rows/block, 16 rows/wave =================
// 12-deep B-frag load batch (bf[12] regs) + A prefetch for k-step pipelining.
__device__ __forceinline__ void gemm1_body(int bid, const float* __restrict__ X,
                                           const short* __restrict__ Wp,
                                           const float* __restrict__ B0,
                                           const float* __restrict__ B1,
                                           const float* __restrict__ B2,
                                           unsigned short* __restrict__ Y0,
                                           unsigned short* __restrict__ Y1,
                                           unsigned short* __restrict__ Y2) {
  const int lane = threadIdx.x & 63;
  const int wave = threadIdx.x >> 6;
  const int r0 = bid * 64 + wave * 16;
  const int m = lane & 15;
  const int q = lane >> 4;
  f32x4 acc[3][4] = {};
  const float* a0 = X + (size_t)min(r0 + m, NN - 1) * 256 + q * 8;
  const short* bp = Wp + lane * 8;
  float4 v0 = *reinterpret_cast<const float4*>(a0);
  float4 v1 = *reinterpret_cast<const float4*>(a0 + 4);
#pragma unroll
  for (int kb = 0; kb < 8; ++kb) {
    s16x8 bf[12];
#pragma unroll
    for (int i = 0; i < 12; ++i)  // 12 independent loads, batched
      bf[i] = *reinterpret_cast<const s16x8*>(bp + (size_t)(kb * 12 + i) * 512);
    s16x8 af;
    af[0] = f2bf(v0.x); af[1] = f2bf(v0.y); af[2] = f2bf(v0.z); af[3] = f2bf(v0.w);
    af[4] = f2bf(v1.x); af[5] = f2bf(v1.y); af[6] = f2bf(v1.z); af[7] = f2bf(v1.w);
    if (kb < 7) {  // prefetch next A step before the MFMA burst
      v0 = *reinterpret_cast<const float4*>(a0 + (kb + 1) * 32);
      v1 = *reinterpret_cast<const float4*>(a0 + (kb + 1) * 32 + 4);
    }
#pragma unroll
    for (int i = 0; i < 12; ++i)
      acc[i >> 2][i & 3] = __builtin_amdgcn_mfma_f32_16x16x32_bf16(
          af, bf[i], acc[i >> 2][i & 3], 0, 0, 0);
  }
#pragma unroll
  for (int w = 0; w < 3; ++w) {
    const float* B = (w == 0) ? B0 : (w == 1) ? B1 : B2;
    unsigned short* Y = (w == 0) ? Y0 : (w == 1) ? Y1 : Y2;
#pragma unroll
    for (int t = 0; t < 4; ++t) {
      const int c = t * 16 + m;
      const float bv = B[c];
#pragma unroll
      for (int rg = 0; rg < 4; ++rg) {
        const int row = r0 + q * 4 + rg;
        if (row < NN)
          Y[(size_t)row * 64 + c] = (unsigned short)f2bf(acc[w][t][rg] + bv);
      }
    }
  }
}

// ====== build_gemm1: gemm1 (blocks 0..781) | CSR Phase B (blocks 782..1172) ======
__global__ __launch_bounds__(256, 2) void build_gemm1(
    const float* __restrict__ X, const short* __restrict__ Wp1,
    const float* __restrict__ B0, const float* __restrict__ B1,
    const float* __restrict__ B2, unsigned short* __restrict__ Y0,
    unsigned short* __restrict__ Y1, unsigned short* __restrict__ Y2,
    const int* __restrict__ gcur, const unsigned* __restrict__ rec,
    int* __restrict__ offsets, unsigned short* __restrict__ csr16) {
  if (blockIdx.x < GB1) {
    gemm1_body(blockIdx.x, X, Wp1, B0, B1, B2, Y0, Y1, Y2);
    return;
  }
  const int b = blockIdx.x - GB1;
  const int tid = threadIdx.x;
  __shared__ unsigned recs[BCAP];
  __shared__ int red[256];
  __shared__ int cnt[128];
  __shared__ int sc[128];
  __shared__ int cur[128];
  int acc = 0;
  for (int t = tid; t < NBKT; t += 256)
    if (t < b) acc += gcur[t];
  red[tid] = acc;
  __syncthreads();
#pragma unroll
  for (int off = 128; off >= 1; off >>= 1) {
    if (tid < off) red[tid] += red[tid + off];
    __syncthreads();
  }
  const int base = red[0];
  const int Tb = min(gcur[b], BCAP);
  if (tid < 128) cnt[tid] = 0;
  __syncthreads();
  for (int i = tid; i < Tb; i += 256) {
    const unsigned k = rec[(size_t)b * BCAP + i];
    recs[i] = k;
    atomicAdd(&cnt[(k >> 16) & 127], 1);
  }
  __syncthreads();
  if (tid < 128) sc[tid] = cnt[tid];
  __syncthreads();
#pragma unroll
  for (int off = 1; off < 128; off <<= 1) {
    int v = (tid < 128 && tid >= off) ? sc[tid - off] : 0;
    __syncthreads();
    if (tid < 128) sc[tid] += v;
    __syncthreads();
  }
  if (tid < 128) {
    const int n = b * 128 + tid;
    if (n < NN) offsets[n + 1] = base + sc[tid];
    cur[tid] = sc[tid] - cnt[tid];
  }
  if (b == 0 && tid == 0) offsets[0] = 0;
  __syncthreads();
  for (int i = tid; i < Tb; i += 256) {
    const unsigned k = recs[i];
    const int p = atomicAdd(&cur[(k >> 16) & 127], 1);
    csr16[base + p] = (unsigned short)(k & 0xFFFFu);
  }
}

// ====== gat1 + gemm2 fused: 16 waves/block = 16 dst rows; H tile in LDS;
// layer-2 triple GEMM done per-block with MFMA (waves 0..11, one 16x16 tile
// each, two chained k-step MFMAs). NN == 3125*16 exactly, no tail. ======
__global__ __launch_bounds__(1024) void gat1_gemm2(
    const unsigned short* __restrict__ XL, const unsigned short* __restrict__ XR,
    const unsigned short* __restrict__ XLIN, const float* __restrict__ att,
    const float* __restrict__ bias, const int* __restrict__ offsets,
    const unsigned short* __restrict__ csr, const short* __restrict__ Wp2,
    const float* __restrict__ B0, const float* __restrict__ B1,
    const float* __restrict__ B2, unsigned short* __restrict__ Y0,
    unsigned short* __restrict__ Y1, unsigned short* __restrict__ Y2) {
  __shared__ unsigned short Hs[16][72];  // +8 pad: 2-way LDS aliasing only
  const int tid = threadIdx.x;
  const int wave = tid >> 6;
  const int lane = tid & 63;
  const int g = lane >> 3;
  const int l = lane & 7;
  const int d = blockIdx.x * 16 + wave;  // < NN always (50000 = 3125*16)
  // ---- GAT aggregation for dst d (identical math to round 10, OC=64) ----
  f32x2 a2[4];
  {
    const float4 t0 = *reinterpret_cast<const float4*>(&att[8 * l]);
    const float4 t1 = *reinterpret_cast<const float4*>(&att[8 * l + 4]);
    a2[0] = (f32x2){t0.x, t0.y}; a2[1] = (f32x2){t0.z, t0.w};
    a2[2] = (f32x2){t1.x, t1.y}; a2[3] = (f32x2){t1.z, t1.w};
  }
  f32x2 xr2[4];
  unp8(*reinterpret_cast<const uint4*>(XR + (size_t)d * 64 + 8 * l), xr2);
  const int beg = offsets[d];
  const int end = offsets[d + 1];
  float D = 0.f;
  f32x2 A2[4] = {};
  const f32x2 ns = (f32x2){NEG_SLOPE, NEG_SLOPE};
  const int nit = (end - beg + 7) >> 3;
  const int i0 = beg + g;
  int sa = (int)csr[(i0 < end) ? i0 : beg];
  uint4 raw_next = *reinterpret_cast<const uint4*>(XL + (size_t)sa * 64 + 8 * l);
  const int i1 = i0 + 8;
  sa = (int)csr[(i1 < end) ? i1 : beg];
  for (int it = 0; it < nit; ++it) {
    const uint4 raw = raw_next;
    const bool act = (beg + it * 8 + g) < end;
    raw_next = *reinterpret_cast<const uint4*>(XL + (size_t)sa * 64 + 8 * l);
    const int i2 = beg + (it + 2) * 8 + g;
    sa = (int)csr[(i2 < end) ? i2 : beg];
    f32x2 xl2[4];
    unp8(raw, xl2);
    f32x2 pacc = (f32x2){0.f, 0.f};
#pragma unroll
    for (int j = 0; j < 4; ++j) {
      const f32x2 t = xl2[j] + xr2[j];
      const f32x2 lr = pk_max(t, t * ns);
      pacc = pk_fma(lr, a2[j], pacc);
    }
    float p = pacc[0] + pacc[1];
    p += __shfl_xor(p, 1, 64);
    p += __shfl_xor(p, 2, 64);
    p += __shfl_xor(p, 4, 64);          // group-uniform logit
    const float w = __expf(act ? p : -INFINITY);  // 0 for inactive slots
    D += w;
    const f32x2 w2 = (f32x2){w, w};
#pragma unroll
    for (int j = 0; j < 4; ++j) A2[j] = pk_fma(w2, xl2[j], A2[j]);
  }
  D += __shfl_xor(D, 8, 64);
  D += __shfl_xor(D, 16, 64);
  D += __shfl_xor(D, 32, 64);
  float A[8];
#pragma unroll
  for (int j = 0; j < 4; ++j) {
#pragma unroll
    for (int c = 0; c < 2; ++c) {
      float v = A2[j][c];
      v += __shfl_xor(v, 8, 64);
      v += __shfl_xor(v, 16, 64);
      v += __shfl_xor(v, 32, 64);
      A[j * 2 + c] = v;
    }
  }
  f32x2 xlin2[4];
  unp8(*reinterpret_cast<const uint4*>(XLIN + (size_t)d * 64 + 8 * l), xlin2);
  float b[8];
  {
    const float4 t0 = *reinterpret_cast<const float4*>(&bias[8 * l]);
    const float4 t1 = *reinterpret_cast<const float4*>(&bias[8 * l + 4]);
    b[0] = t0.x; b[1] = t0.y; b[2] = t0.z; b[3] = t0.w;
    b[4] = t1.x; b[5] = t1.y; b[6] = t1.z; b[7] = t1.w;
  }
  const float inv = 1.0f / D;  // D > 0 (self-loop)
  if (g == 0) {  // relu -> bf16 H row into LDS tile
    float val[8];
#pragma unroll
    for (int j = 0; j < 8; ++j)
      val[j] = fmaxf(fmaf(A[j], inv, b[j]) + xlin2[j >> 1][j & 1], 0.f);
    uint4 o;
    o.x = pack2(val[0], val[1]);
    o.y = pack2(val[2], val[3]);
    o.z = pack2(val[4], val[5]);
    o.w = pack2(val[6], val[7]);
    *reinterpret_cast<uint4*>(&Hs[wave][8 * l]) = o;
  }
  __syncthreads();
  // ---- layer-2 GEMM epilogue: 12 tiles (wsel x t), one per wave ----
  if (wave < 12) {
    const int w = wave >> 2, t = wave & 3;
    const int m = lane & 15, q = lane >> 4;
    const s16x8 af0 = *reinterpret_cast<const s16x8*>(&Hs[m][q * 8]);
    const s16x8 af1 = *reinterpret_cast<const s16x8*>(&Hs[m][32 + q * 8]);
    const short* bp = Wp2 + lane * 8;
    const s16x8 bf0 = *reinterpret_cast<const s16x8*>(bp + (size_t)(w * 4 + t) * 512);
    const s16x8 bf1 = *reinterpret_cast<const s16x8*>(bp + (size_t)((3 + w) * 4 + t) * 512);
    f32x4 acc = {};
    acc = __builtin_amdgcn_mfma_f32_16x16x32_bf16(af0, bf0, acc, 0, 0, 0);
    acc = __builtin_amdgcn_mfma_f32_16x16x32_bf16(af1, bf1, acc, 0, 0, 0);
    const float* B = (w == 0) ? B0 : (w == 1) ? B1 : B2;
    unsigned short* Y = (w == 0) ? Y0 : (w == 1) ? Y1 : Y2;
    const int c = t * 16 + m;
    const float bv = (c < 40) ? B[c] : 0.f;  // pad cols stay exact 0
#pragma unroll
    for (int rg = 0; rg < 4; ++rg) {
      const int row = blockIdx.x * 16 + q * 4 + rg;
      Y[(size_t)row * 64 + c] = (unsigned short)f2bf(acc[rg] + bv);
    }
  }
}

// ====== GATv2 layer-2 aggregation: 8 lanes/edge, 8 edges, log-softmax ======
__global__ __launch_bounds__(256) void gat_agg2(const unsigned short* __restrict__ XL,
                                                const unsigned short* __restrict__ XR,
                                                const unsigned short* __restrict__ XLIN,
                                                const float* __restrict__ att,
                                                const float* __restrict__ bias,
                                                const int* __restrict__ offsets,
                                                const unsigned short* __restrict__ csr,
                                                float* __restrict__ out) {
  const int lane = threadIdx.x & 63;
  const int g = lane >> 3;
  const int l = lane & 7;
  const int d = blockIdx.x * 4 + (threadIdx.x >> 6);
  if (d >= NN) return;
  const bool dimok = (8 * l < CD);
  f32x2 a2[4] = {};
  if (dimok) {
    const float4 t0 = *reinterpret_cast<const float4*>(&att[8 * l]);
    const float4 t1 = *reinterpret_cast<const float4*>(&att[8 * l + 4]);
    a2[0] = (f32x2){t0.x, t0.y}; a2[1] = (f32x2){t0.z, t0.w};
    a2[2] = (f32x2){t1.x, t1.y}; a2[3] = (f32x2){t1.z, t1.w};
  }
  f32x2 xr2[4];
  unp8(*reinterpret_cast<const uint4*>(XR + (size_t)d * 64 + 8 * l), xr2);
  const int beg = offsets[d];
  const int end = offsets[d + 1];
  float D = 0.f;
  f32x2 A2[4] = {};
  const f32x2 ns = (f32x2){NEG_SLOPE, NEG_SLOPE};
  const int nit = (end - beg + 7) >> 3;
  const int i0 = beg + g;
  int sa = (int)csr[(i0 < end) ? i0 : beg];
  uint4 raw_next = *reinterpret_cast<const uint4*>(XL + (size_t)sa * 64 + 8 * l);
  const int i1 = i0 + 8;
  sa = (int)csr[(i1 < end) ? i1 : beg];
  for (int it = 0; it < nit; ++it) {
    const uint4 raw = raw_next;
    const bool act = (beg + it * 8 + g) < end;
    raw_next = *reinterpret_cast<const uint4*>(XL + (size_t)sa * 64 + 8 * l);
    const int i2 = beg + (it + 2) * 8 + g;
    sa = (int)csr[(i2 < end) ? i2 : beg];
    f32x2 xl2[4];
    unp8(raw, xl2);
    f32x2 pacc = (f32x2){0.f, 0.f};
#pragma unroll
    for (int j = 0; j < 4; ++j) {
      const f32x2 t = xl2[j] + xr2[j];
      const f32x2 lr = pk_max(t, t * ns);
      pacc = pk_fma(lr, a2[j], pacc);
    }
    float p = pacc[0] + pacc[1];
    p += __shfl_xor(p, 1, 64);
    p += __shfl_xor(p, 2, 64);
    p += __shfl_xor(p, 4, 64);
    const float w = __expf(act ? p : -INFINITY);
    D += w;
    const f32x2 w2 = (f32x2){w, w};
#pragma unroll
    for (int j = 0; j < 4; ++j) A2[j] = pk_fma(w2, xl2[j], A2[j]);
  }
  D += __shfl_xor(D, 8, 64);
  D += __shfl_xor(D, 16, 64);
  D += __shfl_xor(D, 32, 64);
  float A[8];
#pragma unroll
  for (int j = 0; j < 4; ++j) {
#pragma unroll
    for (int c = 0; c < 2; ++c) {
      float v = A2[j][c];
      v += __shfl_xor(v, 8, 64);
      v += __shfl_xor(v, 16, 64);
      v += __shfl_xor(v, 32, 64);
      A[j * 2 + c] = v;
    }
  }
  f32x2 xlin2[4];
  unp8(*reinterpret_cast<const uint4*>(XLIN + (size_t)d * 64 + 8 * l), xlin2);
  float b[8] = {};
  if (dimok) {
    const float4 t0 = *reinterpret_cast<const float4*>(&bias[8 * l]);
    const float4 t1 = *reinterpret_cast<const float4*>(&bias[8 * l + 4]);
    b[0] = t0.x; b[1] = t0.y; b[2] = t0.z; b[3] = t0.w;
    b[4] = t1.x; b[5] = t1.y; b[6] = t1.z; b[7] = t1.w;
  }
  const float inv = 1.0f / D;
  float val[8];
#pragma unroll
  for (int j = 0; j < 8; ++j)
    val[j] = fmaf(A[j], inv, b[j]) + xlin2[j >> 1][j & 1];
  float mx = -3e38f;
  if (dimok) {
#pragma unroll
    for (int j = 0; j < 8; ++j) mx = fmaxf(mx, val[j]);
  }
  mx = fmaxf(mx, __shfl_xor(mx, 1, 64));
  mx = fmaxf(mx, __shfl_xor(mx, 2, 64));
  mx = fmaxf(mx, __shfl_xor(mx, 4, 64));
  float es = 0.f;
  if (dimok) {
#pragma unroll
    for (int j = 0; j < 8; ++j) es += __expf(val[j] - mx);
  }
  es += __shfl_xor(es, 1, 64);
  es += __shfl_xor(es, 2, 64);
  es += __shfl_xor(es, 4, 64);
  const float lse = mx + __logf(es);
  if (g == 0 && dimok) {
    float4 o0, o1;
    o0.x = val[0] - lse; o0.y = val[1] - lse; o0.z = val[2] - lse; o0.w = val[3] - lse;
    o1.x = val[4] - lse; o1.y = val[5] - lse; o1.z = val[6] - lse; o1.w = val[7] - lse;
    float* dst = &out[(size_t)d * CD + 8 * l];
    *reinterpret_cast<float4*>(dst) = o0;
    *reinterpret_cast<float4*>(dst + 4) = o1;
  }
}

// ---------------- launch ----------------
extern "C" void kernel_launch(void* const* d_in, const int* in_sizes, int n_in,
                              void* d_out, int out_size, void* d_ws, size_t ws_size,
                              hipStream_t stream) {
  const float* x     = (const float*)d_in[0];
  const int*   ei    = (const int*)d_in[1];
  const float* W1l   = (const float*)d_in[2];
  const float* b1l   = (const float*)d_in[3];
  const float* W1r   = (const float*)d_in[4];
  const float* b1r   = (const float*)d_in[5];
  const float* att1  = (const float*)d_in[6];
  const float* bias1 = (const float*)d_in[7];
  const float* lin1W = (const float*)d_in[8];
  const float* lin1b = (const float*)d_in[9];
  const float* W2l   = (const float*)d_in[10];
  const float* b2l   = (const float*)d_in[11];
  const float* W2r   = (const float*)d_in[12];
  const float* b2r   = (const float*)d_in[13];
  const float* att2  = (const float*)d_in[14];
  const float* bias2 = (const float*)d_in[15];
  const float* lin2W = (const float*)d_in[16];
  const float* lin2b = (const float*)d_in[17];
  float* out = (float*)d_out;

  char* ws = (char*)d_ws;
  size_t off = 0;
  auto alloc = [&](size_t bytes) -> void* {
    void* p = ws + off;
    off += (bytes + 255) & ~(size_t)255;
    return p;
  };
  short* Wp1 = (short*)alloc((size_t)TB1 * 2);
  short* Wp2 = (short*)alloc((size_t)TB2 * 2);
  unsigned short* XL1   = (unsigned short*)alloc((size_t)NN * 64 * 2);
  unsigned short* XR1   = (unsigned short*)alloc((size_t)NN * 64 * 2);
  unsigned short* XLIN1 = (unsigned short*)alloc((size_t)NN * 64 * 2);
  unsigned short* XL2   = (unsigned short*)alloc((size_t)NN * 64 * 2);
  unsigned short* XR2   = (unsigned short*)alloc((size_t)NN * 64 * 2);
  unsigned short* XLIN2 = (unsigned short*)alloc((size_t)NN * 64 * 2);
  int* gcur    = (int*)alloc((size_t)NBKT * 4);
  int* offsets = (int*)alloc((size_t)(NN + 1) * 4);
  unsigned* rec = (unsigned*)alloc((size_t)NBKT * BCAP * 4);
  unsigned short* csr = (unsigned short*)alloc((size_t)NITEMS * 2);

  hipMemsetAsync(gcur, 0, (size_t)NBKT * 4, stream);
  prep_bin<<<WPB + NCH, 256, 0, stream>>>(W1l, W1r, lin1W, W2l, W2r, lin2W,
                                          Wp1, Wp2, ei, out + (size_t)NN * CD,
                                          gcur, rec);
  build_gemm1<<<GB1 + NBKT, 256, 0, stream>>>(x, Wp1, b1l, b1r, lin1b,
                                              XL1, XR1, XLIN1, gcur, rec,
                                              offsets, csr);
  gat1_gemm2<<<NN / 16, 1024, 0, stream>>>(XL1, XR1, XLIN1, att1, bias1,
                                           offsets, csr, Wp2, b2l, b2r, lin2b,
                                           XL2, XR2, XLIN2);
  gat_agg2<<<(NN + 3) / 4, 256, 0, stream>>>(XL2, XR2, XLIN2, att2, bias2,
                                             offsets, csr, out);
}